// Round 1
// baseline (10932.187 us; speedup 1.0000x reference)
//
#include <hip/hip_runtime.h>
#include <cstdint>
#include <cstddef>

typedef __attribute__((ext_vector_type(8))) short short8;
typedef __attribute__((ext_vector_type(4))) short short4v;
typedef __attribute__((ext_vector_type(4))) float f32x4;

static constexpr int B_ = 64, T_ = 256, D_ = 1024, NH = 1024, NG = 4096;

__device__ __forceinline__ short f2bs(float f) {
  union { float f; uint32_t u; } cv; cv.f = f;
  uint32_t u = cv.u;
  uint32_t r = (u + 0x7fffu + ((u >> 16) & 1u)) >> 16;  // RNE
  return (short)(uint16_t)r;
}
__device__ __forceinline__ float bs2f(short s) {
  union { uint32_t u; float f; } cv; cv.u = ((uint32_t)(uint16_t)s) << 16; return cv.f;
}

// ---------------------------------------------------------------------------
// xz = x @ W + bias   (M=B*T=16384, K=D=1024, N=4*NH=4096), output bf16 (short)
// 128x128 block tile, 4 waves, 16x16x32 bf16 MFMA.
// A frag: row=lane&15, k=(lane>>4)*8+j ; B frag: col=lane&15, k=(lane>>4)*8+j
// C/D:    col=lane&15, row=(lane>>4)*4+reg   [verified mapping]
// ---------------------------------------------------------------------------
__global__ __launch_bounds__(256) void xz_gemm(const float* __restrict__ x,
                                               const float* __restrict__ W,
                                               const float* __restrict__ bias,
                                               short* __restrict__ xz)
{
  constexpr int BM = 128, BN = 128, BK = 32;
  __shared__ short As[BM][BK];  // [m][k]
  __shared__ short Bs[BK][BN];  // [k][n]
  const int tid  = threadIdx.x;
  const int lane = tid & 63, wave = tid >> 6;
  const int wm = (wave >> 1) * 64, wn = (wave & 1) * 64;
  const int fr = lane & 15, kg = lane >> 4;
  const int bm = blockIdx.x * BM, bn = blockIdx.y * BN;

  f32x4 acc[4][4] = {};

  for (int k0 = 0; k0 < D_; k0 += BK) {
    {  // stage A: 128 rows x 32 k
      const int r0 = tid >> 3, kq = (tid & 7) * 4;
      #pragma unroll
      for (int it = 0; it < 4; ++it) {
        const int row = r0 + it * 32;
        const float4 v = *reinterpret_cast<const float4*>(&x[(size_t)(bm + row) * D_ + k0 + kq]);
        short4v s; s.x = f2bs(v.x); s.y = f2bs(v.y); s.z = f2bs(v.z); s.w = f2bs(v.w);
        *reinterpret_cast<short4v*>(&As[row][kq]) = s;
      }
    }
    {  // stage B: 32 k-rows x 128 n (natural layout, coalesced)
      const int kr0 = tid >> 5, nq = (tid & 31) * 4;
      #pragma unroll
      for (int it = 0; it < 4; ++it) {
        const int krow = kr0 + it * 8;
        const float4 v = *reinterpret_cast<const float4*>(&W[(size_t)(k0 + krow) * NG + bn + nq]);
        short4v s; s.x = f2bs(v.x); s.y = f2bs(v.y); s.z = f2bs(v.z); s.w = f2bs(v.w);
        *reinterpret_cast<short4v*>(&Bs[krow][nq]) = s;
      }
    }
    __syncthreads();

    short8 af[4];
    #pragma unroll
    for (int mi = 0; mi < 4; ++mi)
      af[mi] = *reinterpret_cast<const short8*>(&As[wm + mi * 16 + fr][kg * 8]);
    #pragma unroll
    for (int ni = 0; ni < 4; ++ni) {
      short8 bf;
      #pragma unroll
      for (int j = 0; j < 8; ++j) bf[j] = Bs[kg * 8 + j][wn + ni * 16 + fr];
      #pragma unroll
      for (int mi = 0; mi < 4; ++mi)
        acc[mi][ni] = __builtin_amdgcn_mfma_f32_16x16x32_bf16(af[mi], bf, acc[mi][ni], 0, 0, 0);
    }
    __syncthreads();
  }

  const int fq = lane >> 4;
  #pragma unroll
  for (int ni = 0; ni < 4; ++ni) {
    const int col = bn + wn + ni * 16 + fr;
    const float bv = bias[col];
    #pragma unroll
    for (int mi = 0; mi < 4; ++mi) {
      const int rowb = bm + wm + mi * 16 + fq * 4;
      #pragma unroll
      for (int r = 0; r < 4; ++r)
        xz[(size_t)(rowb + r) * NG + col] = f2bs(acc[mi][ni][r] + bv);
    }
  }
}

// ---------------------------------------------------------------------------
// One LSTM timestep. Grid: 256 blocks (u-slice of 4), 512 threads:
//   b = tid&63, ks = tid>>6 (8-way k split, 128 k each).
// Each thread accumulates z[b, u0..u0+3, 4 gates] over its k range;
// LDS reduction across ks; threads 0..63 do gate math and writes.
// hT is a transposed, k-packed bf16 h buffer: hT[(u>>3)*512 + b*8 + (u&7)].
// ---------------------------------------------------------------------------
__global__ __launch_bounds__(512) void lstm_step(const short* __restrict__ xz,
                                                 const float* __restrict__ U,
                                                 const short* __restrict__ hT_in,
                                                 short* __restrict__ hT_out,
                                                 float* __restrict__ cbuf,
                                                 float* __restrict__ out,
                                                 int t)
{
  __shared__ float red[512][17];
  const int tid = threadIdx.x;
  const int b   = tid & 63;
  const int ks  = tid >> 6;          // 0..7
  const int u0  = blockIdx.x * 4;

  float acc[4][4] = {};              // [gate][uj]
  if (t > 0) {
    const float* __restrict__ up0 = &U[(size_t)(ks * 128) * NG + u0];
    const short* __restrict__ hp  = &hT_in[(ks * 16) * 512 + b * 8];
    for (int kt = 0; kt < 16; ++kt) {
      const short8 hv = *reinterpret_cast<const short8*>(hp + (size_t)kt * 512);
      #pragma unroll
      for (int kk = 0; kk < 8; ++kk) {
        const float hk = bs2f(hv[kk]);
        const float* up = up0 + (size_t)(kt * 8 + kk) * NG;
        #pragma unroll
        for (int g = 0; g < 4; ++g) {
          const float4 uv = *reinterpret_cast<const float4*>(up + g * NH);
          acc[g][0] = fmaf(hk, uv.x, acc[g][0]);
          acc[g][1] = fmaf(hk, uv.y, acc[g][1]);
          acc[g][2] = fmaf(hk, uv.z, acc[g][2]);
          acc[g][3] = fmaf(hk, uv.w, acc[g][3]);
        }
      }
    }
  }
  #pragma unroll
  for (int g = 0; g < 4; ++g)
    #pragma unroll
    for (int j = 0; j < 4; ++j) red[tid][g * 4 + j] = acc[g][j];
  __syncthreads();

  if (tid < 64) {
    float z[4][4];
    #pragma unroll
    for (int g = 0; g < 4; ++g)
      #pragma unroll
      for (int j = 0; j < 4; ++j) {
        float s = 0.f;
        #pragma unroll
        for (int q = 0; q < 8; ++q) s += red[q * 64 + tid][g * 4 + j];
        z[g][j] = s;
      }
    const size_t xzbase = ((size_t)tid * T_ + t) * NG + u0;
    float hnv[4], cnv[4];
    #pragma unroll
    for (int j = 0; j < 4; ++j) {
      const float zi = z[0][j] + bs2f(xz[xzbase + j]);
      const float zf = z[1][j] + bs2f(xz[xzbase + NH + j]);
      const float zg = z[2][j] + bs2f(xz[xzbase + 2 * NH + j]);
      const float zo = z[3][j] + bs2f(xz[xzbase + 3 * NH + j]);
      const float ig = 1.f / (1.f + __expf(-zi));
      const float fg = 1.f / (1.f + __expf(-zf));
      const float gg = tanhf(zg);
      const float og = 1.f / (1.f + __expf(-zo));
      const float cold = (t > 0) ? cbuf[tid * NH + u0 + j] : 0.f;
      const float cc = fg * cold + ig * gg;
      const float hh = og * tanhf(cc);
      cnv[j] = cc; hnv[j] = hh;
    }
    float4 cv; cv.x = cnv[0]; cv.y = cnv[1]; cv.z = cnv[2]; cv.w = cnv[3];
    *reinterpret_cast<float4*>(&cbuf[tid * NH + u0]) = cv;
    float4 hv; hv.x = hnv[0]; hv.y = hnv[1]; hv.z = hnv[2]; hv.w = hnv[3];
    *reinterpret_cast<float4*>(&out[((size_t)tid * T_ + t) * NH + u0]) = hv;
    short4v hs; hs.x = f2bs(hnv[0]); hs.y = f2bs(hnv[1]); hs.z = f2bs(hnv[2]); hs.w = f2bs(hnv[3]);
    *reinterpret_cast<short4v*>(&hT_out[(u0 >> 3) * 512 + tid * 8 + (u0 & 7)]) = hs;
  }
}

extern "C" void kernel_launch(void* const* d_in, const int* in_sizes, int n_in,
                              void* d_out, int out_size, void* d_ws, size_t ws_size,
                              hipStream_t stream) {
  const float* x    = (const float*)d_in[0];
  const float* W    = (const float*)d_in[1];
  const float* U    = (const float*)d_in[2];
  const float* bias = (const float*)d_in[3];
  float* out = (float*)d_out;
  char* ws = (char*)d_ws;

  // ws layout: xz bf16 [16384][4096] = 128 MiB; hT ping/pong 2x128 KiB; c 256 KiB
  short* xz   = (short*)ws;
  short* hTa  = (short*)(ws + 134217728);
  short* hTb  = (short*)(ws + 134348800);
  float* cbuf = (float*)(ws + 134479872);

  xz_gemm<<<dim3(128, 32), 256, 0, stream>>>(x, W, bias, xz);
  for (int t = 0; t < T_; ++t) {
    const short* hin = (t & 1) ? hTb : hTa;
    short*       hout = (t & 1) ? hTa : hTb;
    lstm_step<<<dim3(256), 512, 0, stream>>>(xz, U, hin, hout, cbuf, out, t);
  }
}

// Round 2
// 9379.484 us; speedup vs baseline: 1.1655x; 1.1655x over previous
//
#include <hip/hip_runtime.h>
#include <hip/hip_cooperative_groups.h>
#include <cstdint>
#include <cstddef>

namespace cg = cooperative_groups;

typedef __attribute__((ext_vector_type(8))) short short8;
typedef __attribute__((ext_vector_type(4))) short short4v;
typedef __attribute__((ext_vector_type(4))) float f32x4;

static constexpr int B_ = 64, T_ = 256, D_ = 1024, NH = 1024, NG = 4096;

__device__ __forceinline__ short f2bs(float f) {
  union { float f; uint32_t u; } cv; cv.f = f;
  uint32_t u = cv.u;
  uint32_t r = (u + 0x7fffu + ((u >> 16) & 1u)) >> 16;  // RNE
  return (short)(uint16_t)r;
}
__device__ __forceinline__ float bs2f(short s) {
  union { uint32_t u; float f; } cv; cv.u = ((uint32_t)(uint16_t)s) << 16; return cv.f;
}

// ---------------------------------------------------------------------------
// xz = x @ W + bias   (M=16384, K=1024, N=4096), bf16 out. Unchanged from R0.
// ---------------------------------------------------------------------------
__global__ __launch_bounds__(256) void xz_gemm(const float* __restrict__ x,
                                               const float* __restrict__ W,
                                               const float* __restrict__ bias,
                                               short* __restrict__ xz)
{
  constexpr int BM = 128, BN = 128, BK = 32;
  __shared__ short As[BM][BK];
  __shared__ short Bs[BK][BN];
  const int tid  = threadIdx.x;
  const int lane = tid & 63, wave = tid >> 6;
  const int wm = (wave >> 1) * 64, wn = (wave & 1) * 64;
  const int fr = lane & 15, kg = lane >> 4;
  const int bm = blockIdx.x * BM, bn = blockIdx.y * BN;

  f32x4 acc[4][4] = {};

  for (int k0 = 0; k0 < D_; k0 += BK) {
    {
      const int r0 = tid >> 3, kq = (tid & 7) * 4;
      #pragma unroll
      for (int it = 0; it < 4; ++it) {
        const int row = r0 + it * 32;
        const float4 v = *reinterpret_cast<const float4*>(&x[(size_t)(bm + row) * D_ + k0 + kq]);
        short4v s; s.x = f2bs(v.x); s.y = f2bs(v.y); s.z = f2bs(v.z); s.w = f2bs(v.w);
        *reinterpret_cast<short4v*>(&As[row][kq]) = s;
      }
    }
    {
      const int kr0 = tid >> 5, nq = (tid & 31) * 4;
      #pragma unroll
      for (int it = 0; it < 4; ++it) {
        const int krow = kr0 + it * 8;
        const float4 v = *reinterpret_cast<const float4*>(&W[(size_t)(k0 + krow) * NG + bn + nq]);
        short4v s; s.x = f2bs(v.x); s.y = f2bs(v.y); s.z = f2bs(v.z); s.w = f2bs(v.w);
        *reinterpret_cast<short4v*>(&Bs[krow][nq]) = s;
      }
    }
    __syncthreads();

    short8 af[4];
    #pragma unroll
    for (int mi = 0; mi < 4; ++mi)
      af[mi] = *reinterpret_cast<const short8*>(&As[wm + mi * 16 + fr][kg * 8]);
    #pragma unroll
    for (int ni = 0; ni < 4; ++ni) {
      short8 bf;
      #pragma unroll
      for (int j = 0; j < 8; ++j) bf[j] = Bs[kg * 8 + j][wn + ni * 16 + fr];
      #pragma unroll
      for (int mi = 0; mi < 4; ++mi)
        acc[mi][ni] = __builtin_amdgcn_mfma_f32_16x16x32_bf16(af[mi], bf, acc[mi][ni], 0, 0, 0);
    }
    __syncthreads();
  }

  const int fq = lane >> 4;
  #pragma unroll
  for (int ni = 0; ni < 4; ++ni) {
    const int col = bn + wn + ni * 16 + fr;
    const float bv = bias[col];
    #pragma unroll
    for (int mi = 0; mi < 4; ++mi) {
      const int rowb = bm + wm + mi * 16 + fq * 4;
      #pragma unroll
      for (int r = 0; r < 4; ++r)
        xz[(size_t)(rowb + r) * NG + col] = f2bs(acc[mi][ni][r] + bv);
    }
  }
}

// ---------------------------------------------------------------------------
// Persistent recurrence: 256 blocks (1/CU) x 512 threads, one grid.sync/step.
// Block owns units [4*bid, 4*bid+4) -> 16 gate cols (col = g*4 + uj).
// U slice staged in LDS as bf16 hi/lo split (fp32-equivalent accuracy).
// Per step: 8 waves (m-tile = wave&3, K-half = wave>>2) x 16 k-steps x 2 MFMA;
// 2-way cross-wave LDS reduce; 256 threads gate math; h ping-pong in global.
// ---------------------------------------------------------------------------
__global__ __launch_bounds__(512) void lstm_persist(const short* __restrict__ xz,
                                                    const float* __restrict__ U,
                                                    short* __restrict__ h0buf,
                                                    short* __restrict__ h1buf,
                                                    float* __restrict__ out)
{
  __shared__ short UsH[128 * 16 * 8];   // [kb][col][kj] = 32 KiB
  __shared__ short UsL[128 * 16 * 8];   // 32 KiB
  __shared__ float part[4][64][4];      // partials from K-half 1 waves
  __shared__ float zsm[64][16];         // z for gate math
  __shared__ float csm[64][4];          // persistent cell state

  const int tid  = threadIdx.x;
  const int lane = tid & 63, wave = tid >> 6;
  const int u0 = blockIdx.x * 4;
  const int fr = lane & 15, kg = lane >> 4;
  const int mt = wave & 3;    // batch tile (16 rows)
  const int kh = wave >> 2;   // K half (512 k each)

  // Stage U slice once: col c = g*4+uj ; packed [k>>3][c][k&7] for short8 B-frags.
  for (int idx = tid; idx < 1024 * 16; idx += 512) {
    const int k = idx >> 4, c = idx & 15;
    const int g = c >> 2, uj = c & 3;
    const float v = U[(size_t)k * NG + g * NH + u0 + uj];
    const short hi = f2bs(v);
    const short lo = f2bs(v - bs2f(hi));
    const int off = ((k >> 3) * 16 + c) * 8 + (k & 7);
    UsH[off] = hi; UsL[off] = lo;
  }
  if (tid < 256) csm[tid >> 2][tid & 3] = 0.f;
  __syncthreads();

  cg::grid_group grid = cg::this_grid();

  for (int t = 0; t < T_; ++t) {
    // h(t) goes to buf[t&1]; h(t-1) is in buf[(t+1)&1]
    const short* __restrict__ hprev = (t & 1) ? h0buf : h1buf;
    short* __restrict__ hnext       = (t & 1) ? h1buf : h0buf;

    f32x4 acc = {0.f, 0.f, 0.f, 0.f};
    if (t > 0) {
      const short* __restrict__ hrow = &hprev[(size_t)(mt * 16 + fr) * NH];
      #pragma unroll
      for (int ks = 0; ks < 16; ++ks) {
        const int k0 = kh * 512 + ks * 32;
        const short8 af = *reinterpret_cast<const short8*>(&hrow[k0 + kg * 8]);
        const int boff = (((k0 >> 3) + kg) * 16 + fr) * 8;
        const short8 bh = *reinterpret_cast<const short8*>(&UsH[boff]);
        const short8 bl = *reinterpret_cast<const short8*>(&UsL[boff]);
        acc = __builtin_amdgcn_mfma_f32_16x16x32_bf16(af, bh, acc, 0, 0, 0);
        acc = __builtin_amdgcn_mfma_f32_16x16x32_bf16(af, bl, acc, 0, 0, 0);
      }
    }
    if (kh == 1) {
      #pragma unroll
      for (int r = 0; r < 4; ++r) part[mt][lane][r] = acc[r];
    }
    __syncthreads();
    if (kh == 0) {
      // C/D mapping: col = lane&15, row = (lane>>4)*4 + r
      #pragma unroll
      for (int r = 0; r < 4; ++r)
        zsm[mt * 16 + kg * 4 + r][fr] = acc[r] + part[mt][lane][r];
    }
    __syncthreads();

    if (tid < 256) {
      const int b = tid >> 2, uj = tid & 3;
      const size_t xb = ((size_t)b * T_ + t) * NG + u0 + uj;
      const float zi = zsm[b][0  + uj] + bs2f(xz[xb]);
      const float zf = zsm[b][4  + uj] + bs2f(xz[xb + NH]);
      const float zg = zsm[b][8  + uj] + bs2f(xz[xb + 2 * NH]);
      const float zo = zsm[b][12 + uj] + bs2f(xz[xb + 3 * NH]);
      const float ig = 1.f / (1.f + __expf(-zi));
      const float fg = 1.f / (1.f + __expf(-zf));
      const float gg = tanhf(zg);
      const float og = 1.f / (1.f + __expf(-zo));
      const float cc = fg * csm[b][uj] + ig * gg;
      const float hh = og * tanhf(cc);
      csm[b][uj] = cc;
      out[((size_t)b * T_ + t) * NH + u0 + uj] = hh;
      hnext[(size_t)b * NH + u0 + uj] = f2bs(hh);
    }
    grid.sync();
  }
}

extern "C" void kernel_launch(void* const* d_in, const int* in_sizes, int n_in,
                              void* d_out, int out_size, void* d_ws, size_t ws_size,
                              hipStream_t stream) {
  const float* x    = (const float*)d_in[0];
  const float* W    = (const float*)d_in[1];
  const float* U    = (const float*)d_in[2];
  const float* bias = (const float*)d_in[3];
  float* out = (float*)d_out;
  char* ws = (char*)d_ws;

  // ws layout: xz bf16 [16384][4096] = 128 MiB; h ping/pong 2 x 128 KiB
  short* xz = (short*)ws;
  short* hA = (short*)(ws + 134217728);
  short* hB = (short*)(ws + 134348800);

  xz_gemm<<<dim3(128, 32), 256, 0, stream>>>(x, W, bias, xz);

  const short* xzc = xz;
  void* kargs[] = { (void*)&xzc, (void*)&U, (void*)&hA, (void*)&hB, (void*)&out };
  hipLaunchCooperativeKernel((void*)lstm_persist, dim3(256), dim3(512), kargs, 0, stream);
}

// Round 3
// 3941.209 us; speedup vs baseline: 2.7738x; 2.3798x over previous
//
#include <hip/hip_runtime.h>
#include <hip/hip_cooperative_groups.h>
#include <cstdint>
#include <cstddef>

typedef __attribute__((ext_vector_type(8))) short short8;
typedef __attribute__((ext_vector_type(4))) short short4v;
typedef __attribute__((ext_vector_type(4))) float f32x4;

static constexpr int B_ = 64, T_ = 256, D_ = 1024, NH = 1024, NG = 4096;
static constexpr int NBLK = 128;           // recurrence blocks, 8 units each
static constexpr int LDS_BYTES = 65536 + 65536 + 8448 + 2048;  // UsH,UsL,zsm(pad33),csm

__device__ __forceinline__ short f2bs(float f) {
  union { float f; uint32_t u; } cv; cv.f = f;
  uint32_t u = cv.u;
  uint32_t r = (u + 0x7fffu + ((u >> 16) & 1u)) >> 16;  // RNE
  return (short)(uint16_t)r;
}
__device__ __forceinline__ float bs2f(short s) {
  union { uint32_t u; float f; } cv; cv.u = ((uint32_t)(uint16_t)s) << 16; return cv.f;
}

// ---------------------------------------------------------------------------
// xz = x @ W + bias  (M=16384,K=1024,N=4096), bf16, scattered to step-major
// layout: xzT[((ublk*256 + t)*64 + b)*32 + g*8 + uj]   (ublk=u>>3, uj=u&7)
// ---------------------------------------------------------------------------
__global__ __launch_bounds__(256) void xz_gemm(const float* __restrict__ x,
                                               const float* __restrict__ W,
                                               const float* __restrict__ bias,
                                               short* __restrict__ xzT)
{
  constexpr int BM = 128, BN = 128, BK = 32;
  __shared__ short As[BM][BK];
  __shared__ short Bs[BK][BN];
  const int tid  = threadIdx.x;
  const int lane = tid & 63, wave = tid >> 6;
  const int wm = (wave >> 1) * 64, wn = (wave & 1) * 64;
  const int fr = lane & 15, kg = lane >> 4;
  const int bm = blockIdx.x * BM, bn = blockIdx.y * BN;

  f32x4 acc[4][4] = {};

  for (int k0 = 0; k0 < D_; k0 += BK) {
    {
      const int r0 = tid >> 3, kq = (tid & 7) * 4;
      #pragma unroll
      for (int it = 0; it < 4; ++it) {
        const int row = r0 + it * 32;
        const float4 v = *reinterpret_cast<const float4*>(&x[(size_t)(bm + row) * D_ + k0 + kq]);
        short4v s; s.x = f2bs(v.x); s.y = f2bs(v.y); s.z = f2bs(v.z); s.w = f2bs(v.w);
        *reinterpret_cast<short4v*>(&As[row][kq]) = s;
      }
    }
    {
      const int kr0 = tid >> 5, nq = (tid & 31) * 4;
      #pragma unroll
      for (int it = 0; it < 4; ++it) {
        const int krow = kr0 + it * 8;
        const float4 v = *reinterpret_cast<const float4*>(&W[(size_t)(k0 + krow) * NG + bn + nq]);
        short4v s; s.x = f2bs(v.x); s.y = f2bs(v.y); s.z = f2bs(v.z); s.w = f2bs(v.w);
        *reinterpret_cast<short4v*>(&Bs[krow][nq]) = s;
      }
    }
    __syncthreads();

    short8 af[4];
    #pragma unroll
    for (int mi = 0; mi < 4; ++mi)
      af[mi] = *reinterpret_cast<const short8*>(&As[wm + mi * 16 + fr][kg * 8]);
    #pragma unroll
    for (int ni = 0; ni < 4; ++ni) {
      short8 bf;
      #pragma unroll
      for (int j = 0; j < 8; ++j) bf[j] = Bs[kg * 8 + j][wn + ni * 16 + fr];
      #pragma unroll
      for (int mi = 0; mi < 4; ++mi)
        acc[mi][ni] = __builtin_amdgcn_mfma_f32_16x16x32_bf16(af[mi], bf, acc[mi][ni], 0, 0, 0);
    }
    __syncthreads();
  }

  const int fq = lane >> 4;
  #pragma unroll
  for (int ni = 0; ni < 4; ++ni) {
    const int col = bn + wn + ni * 16 + fr;
    const int g = col >> 10, u = col & 1023;
    const int ublk = u >> 3, uj = u & 7;
    const float bv = bias[col];
    #pragma unroll
    for (int mi = 0; mi < 4; ++mi) {
      const int rowb = bm + wm + mi * 16 + fq * 4;
      #pragma unroll
      for (int r = 0; r < 4; ++r) {
        const int row = rowb + r;
        const int b = row >> 8, t = row & 255;
        xzT[((size_t)(ublk * 256 + t) * 64 + b) * 32 + g * 8 + uj] = f2bs(acc[mi][ni][r] + bv);
      }
    }
  }
}

// ---------------------------------------------------------------------------
// Persistent recurrence: 128 blocks x 512 threads. Block owns units
// [8*bid, 8*bid+8) -> 32 gate cols (c = g*8+uj). U hi/lo bf16 in LDS.
// 8 waves: (mt=wave&3, nt=wave>>2), full K=1024 -> 64 MFMA/wave/step.
// Hand-rolled flag barrier (release-fence + relaxed flags + acquire-fence).
// ---------------------------------------------------------------------------
__global__ __launch_bounds__(512) void lstm_persist(const short* __restrict__ xzT,
                                                    const float* __restrict__ U,
                                                    short* __restrict__ h0buf,
                                                    short* __restrict__ h1buf,
                                                    int* __restrict__ flags,
                                                    float* __restrict__ out)
{
  extern __shared__ char smem[];
  short* UsH = (short*)smem;                       // [k>>3][c][k&7] 64 KiB
  short* UsL = (short*)(smem + 65536);             // 64 KiB
  float* zsm = (float*)(smem + 131072);            // [64][33] pad
  float* csm = (float*)(smem + 131072 + 8448);     // [64][8]

  const int tid  = threadIdx.x;
  const int lane = tid & 63, wave = tid >> 6;
  const int bid  = blockIdx.x;
  const int u0   = bid * 8;
  const int fr = lane & 15, kg = lane >> 4;
  const int mt = wave & 3;      // batch tile (16 rows)
  const int nt = wave >> 2;     // col tile (16 of 32 cols)
  const int gb = tid >> 3, guj = tid & 7;  // gate-math mapping

  // Stage U slice once (hi/lo split ~= fp32 accuracy).
  for (int idx = tid; idx < 1024 * 32; idx += 512) {
    const int k = idx >> 5, c = idx & 31;
    const int g = c >> 3, uj = c & 7;
    const float v = U[(size_t)k * NG + g * NH + u0 + uj];
    const short hi = f2bs(v);
    const short lo = f2bs(v - bs2f(hi));
    const int off = ((k >> 3) * 32 + c) * 8 + (k & 7);
    UsH[off] = hi; UsL[off] = lo;
  }
  csm[tid] = 0.f; if (tid < 512) {}  // 64*8 = 512 exactly
  __syncthreads();

  for (int t = 0; t < T_; ++t) {
    const short* __restrict__ hprev = (t & 1) ? h0buf : h1buf;
    short* __restrict__ hnext       = (t & 1) ? h1buf : h0buf;

    // Prefetch this step's xz (4 KiB contiguous block, issued before MFMA).
    const size_t xzb = ((size_t)(bid * 256 + t) * 64 + gb) * 32 + guj;
    const float xzi = bs2f(xzT[xzb]);
    const float xzf = bs2f(xzT[xzb + 8]);
    const float xzg = bs2f(xzT[xzb + 16]);
    const float xzo = bs2f(xzT[xzb + 24]);

    if (t > 0) {
      f32x4 acc = {0.f, 0.f, 0.f, 0.f};
      const short* __restrict__ hrow = &hprev[(size_t)(mt * 16 + fr) * NH];
      #pragma unroll
      for (int ks = 0; ks < 32; ++ks) {
        const short8 af = *reinterpret_cast<const short8*>(&hrow[ks * 32 + kg * 8]);
        const int boff = ((ks * 4 + kg) * 32 + nt * 16 + fr) * 8;
        const short8 bh = *reinterpret_cast<const short8*>(&UsH[boff]);
        const short8 bl = *reinterpret_cast<const short8*>(&UsL[boff]);
        acc = __builtin_amdgcn_mfma_f32_16x16x32_bf16(af, bh, acc, 0, 0, 0);
        acc = __builtin_amdgcn_mfma_f32_16x16x32_bf16(af, bl, acc, 0, 0, 0);
      }
      // C/D mapping: col = lane&15, row = (lane>>4)*4 + r
      #pragma unroll
      for (int r = 0; r < 4; ++r)
        zsm[(mt * 16 + kg * 4 + r) * 33 + nt * 16 + fr] = acc[r];
    }
    __syncthreads();

    {  // gate math: all 512 threads, (b=gb, uj=guj)
      const float zi = xzi + ((t > 0) ? zsm[gb * 33 + guj]      : 0.f);
      const float zf = xzf + ((t > 0) ? zsm[gb * 33 + 8 + guj]  : 0.f);
      const float zg = xzg + ((t > 0) ? zsm[gb * 33 + 16 + guj] : 0.f);
      const float zo = xzo + ((t > 0) ? zsm[gb * 33 + 24 + guj] : 0.f);
      const float ig = 1.f / (1.f + __expf(-zi));
      const float fg = 1.f / (1.f + __expf(-zf));
      const float gg = tanhf(zg);
      const float og = 1.f / (1.f + __expf(-zo));
      const float cc = fg * csm[tid] + ig * gg;
      const float hh = og * tanhf(cc);
      csm[tid] = cc;
      out[((size_t)gb * T_ + t) * NH + u0 + guj] = hh;
      hnext[(size_t)gb * NH + u0 + guj] = f2bs(hh);
    }

    if (t < T_ - 1) {
      __syncthreads();
      if (tid == 0) {
        __builtin_amdgcn_fence(__ATOMIC_RELEASE, "agent");
        __hip_atomic_store(&flags[bid * 16], t + 1, __ATOMIC_RELAXED, __HIP_MEMORY_SCOPE_AGENT);
      }
      if (tid < NBLK) {
        while (__hip_atomic_load(&flags[tid * 16], __ATOMIC_RELAXED, __HIP_MEMORY_SCOPE_AGENT) < t + 1)
          __builtin_amdgcn_s_sleep(1);
      }
      __syncthreads();
      if (tid == 0) __builtin_amdgcn_fence(__ATOMIC_ACQUIRE, "agent");
      __syncthreads();
    }
  }
}

extern "C" void kernel_launch(void* const* d_in, const int* in_sizes, int n_in,
                              void* d_out, int out_size, void* d_ws, size_t ws_size,
                              hipStream_t stream) {
  const float* x    = (const float*)d_in[0];
  const float* W    = (const float*)d_in[1];
  const float* U    = (const float*)d_in[2];
  const float* bias = (const float*)d_in[3];
  float* out = (float*)d_out;
  char* ws = (char*)d_ws;

  // ws: xzT bf16 128 MiB | flags 8 KiB | h ping/pong 2 x 128 KiB
  short* xzT  = (short*)ws;
  int*   flags = (int*)(ws + 134217728);
  short* hA   = (short*)(ws + 134225920);
  short* hB   = (short*)(ws + 134356992);

  hipMemsetAsync(flags, 0, NBLK * 16 * sizeof(int), stream);
  xz_gemm<<<dim3(128, 32), 256, 0, stream>>>(x, W, bias, xzT);

  hipFuncSetAttribute((const void*)lstm_persist,
                      hipFuncAttributeMaxDynamicSharedMemorySize, LDS_BYTES);
  const short* xzc = xzT;
  void* kargs[] = { (void*)&xzc, (void*)&U, (void*)&hA, (void*)&hB,
                    (void*)&flags, (void*)&out };
  hipLaunchCooperativeKernel((void*)lstm_persist, dim3(NBLK), dim3(512),
                             kargs, LDS_BYTES, stream);
}

// Round 4
// 2962.753 us; speedup vs baseline: 3.6899x; 1.3303x over previous
//
#include <hip/hip_runtime.h>
#include <cstdint>
#include <cstddef>

typedef __attribute__((ext_vector_type(8))) short short8;
typedef __attribute__((ext_vector_type(4))) short short4v;
typedef __attribute__((ext_vector_type(4))) float f32x4;

static constexpr int B_ = 64, T_ = 256, D_ = 1024, NH = 1024, NG = 4096;
static constexpr int NBLK = 128;   // recurrence blocks, 8 units each
static constexpr int LDS_BYTES = 65536 + 65536 + 8448 + 2048;  // UsH,UsL,zsm(pad33),csm

__device__ __forceinline__ short f2bs(float f) {
  union { float f; uint32_t u; } cv; cv.f = f;
  uint32_t u = cv.u;
  uint32_t r = (u + 0x7fffu + ((u >> 16) & 1u)) >> 16;  // RNE
  return (short)(uint16_t)r;
}
__device__ __forceinline__ float bs2f(short s) {
  union { uint32_t u; float f; } cv; cv.u = ((uint32_t)(uint16_t)s) << 16; return cv.f;
}
__device__ __forceinline__ float fsigm(float x) {
  return __builtin_amdgcn_rcpf(1.f + __expf(-x));
}
__device__ __forceinline__ float ftanh(float x) {
  return 1.f - 2.f * __builtin_amdgcn_rcpf(__expf(2.f * x) + 1.f);
}

// ---------------------------------------------------------------------------
// xz = x @ W + bias  (M=16384,K=1024,N=4096), bf16, scattered step-major:
// xzT[((ublk*256 + t)*64 + b)*32 + uj*4 + g]   (ublk=u>>3, uj=u&7, g=gate)
// ---------------------------------------------------------------------------
__global__ __launch_bounds__(256) void xz_gemm(const float* __restrict__ x,
                                               const float* __restrict__ W,
                                               const float* __restrict__ bias,
                                               short* __restrict__ xzT)
{
  constexpr int BM = 128, BN = 128, BK = 32;
  __shared__ short As[BM][BK];
  __shared__ short Bs[BK][BN];
  const int tid  = threadIdx.x;
  const int lane = tid & 63, wave = tid >> 6;
  const int wm = (wave >> 1) * 64, wn = (wave & 1) * 64;
  const int fr = lane & 15, kg = lane >> 4;
  const int bm = blockIdx.x * BM, bn = blockIdx.y * BN;

  f32x4 acc[4][4] = {};

  for (int k0 = 0; k0 < D_; k0 += BK) {
    {
      const int r0 = tid >> 3, kq = (tid & 7) * 4;
      #pragma unroll
      for (int it = 0; it < 4; ++it) {
        const int row = r0 + it * 32;
        const float4 v = *reinterpret_cast<const float4*>(&x[(size_t)(bm + row) * D_ + k0 + kq]);
        short4v s; s.x = f2bs(v.x); s.y = f2bs(v.y); s.z = f2bs(v.z); s.w = f2bs(v.w);
        *reinterpret_cast<short4v*>(&As[row][kq]) = s;
      }
    }
    {
      const int kr0 = tid >> 5, nq = (tid & 31) * 4;
      #pragma unroll
      for (int it = 0; it < 4; ++it) {
        const int krow = kr0 + it * 8;
        const float4 v = *reinterpret_cast<const float4*>(&W[(size_t)(k0 + krow) * NG + bn + nq]);
        short4v s; s.x = f2bs(v.x); s.y = f2bs(v.y); s.z = f2bs(v.z); s.w = f2bs(v.w);
        *reinterpret_cast<short4v*>(&Bs[krow][nq]) = s;
      }
    }
    __syncthreads();

    short8 af[4];
    #pragma unroll
    for (int mi = 0; mi < 4; ++mi)
      af[mi] = *reinterpret_cast<const short8*>(&As[wm + mi * 16 + fr][kg * 8]);
    #pragma unroll
    for (int ni = 0; ni < 4; ++ni) {
      short8 bf;
      #pragma unroll
      for (int j = 0; j < 8; ++j) bf[j] = Bs[kg * 8 + j][wn + ni * 16 + fr];
      #pragma unroll
      for (int mi = 0; mi < 4; ++mi)
        acc[mi][ni] = __builtin_amdgcn_mfma_f32_16x16x32_bf16(af[mi], bf, acc[mi][ni], 0, 0, 0);
    }
    __syncthreads();
  }

  const int fq = lane >> 4;
  #pragma unroll
  for (int ni = 0; ni < 4; ++ni) {
    const int col = bn + wn + ni * 16 + fr;
    const int g = col >> 10, u = col & 1023;
    const int ublk = u >> 3, uj = u & 7;
    const float bv = bias[col];
    #pragma unroll
    for (int mi = 0; mi < 4; ++mi) {
      const int rowb = bm + wm + mi * 16 + fq * 4;
      #pragma unroll
      for (int r = 0; r < 4; ++r) {
        const int row = rowb + r;
        const int b = row >> 8, t = row & 255;
        xzT[((size_t)(ublk * 256 + t) * 64 + b) * 32 + uj * 4 + g] = f2bs(acc[mi][ni][r] + bv);
      }
    }
  }
}

// ---------------------------------------------------------------------------
// Persistent recurrence, fence-free cross-XCD coherence:
//  - h stores:  global_store_dword sc0 sc1 (write-through) + vmcnt drain
//  - h loads:   global_load_dwordx4 sc0 sc1 (read-around stale caches)
//  - flags:     relaxed agent atomics; poll per 256-k chunk (32 producers),
//               pipelined 2-deep with counted vmcnt(8).
// 128 blocks x 512 thr; block owns 8 units (32 gate cols); U hi/lo in LDS.
// ---------------------------------------------------------------------------
#define H_ISSUE(BUF, O0,O1,O2,O3,O4,O5,O6,O7) \
  asm volatile( \
    "global_load_dwordx4 %0, %8, off offset:" #O0 " sc0 sc1\n\t" \
    "global_load_dwordx4 %1, %8, off offset:" #O1 " sc0 sc1\n\t" \
    "global_load_dwordx4 %2, %8, off offset:" #O2 " sc0 sc1\n\t" \
    "global_load_dwordx4 %3, %8, off offset:" #O3 " sc0 sc1\n\t" \
    "global_load_dwordx4 %4, %8, off offset:" #O4 " sc0 sc1\n\t" \
    "global_load_dwordx4 %5, %8, off offset:" #O5 " sc0 sc1\n\t" \
    "global_load_dwordx4 %6, %8, off offset:" #O6 " sc0 sc1" \
    "\n\tglobal_load_dwordx4 %7, %8, off offset:" #O7 " sc0 sc1" \
    : "=&v"(BUF[0]), "=&v"(BUF[1]), "=&v"(BUF[2]), "=&v"(BUF[3]), \
      "=&v"(BUF[4]), "=&v"(BUF[5]), "=&v"(BUF[6]), "=&v"(BUF[7]) \
    : "v"(hp) : "memory")

#define WAITV(N) do { asm volatile("s_waitcnt vmcnt(" #N ")" ::: "memory"); \
                      __builtin_amdgcn_sched_barrier(0); } while (0)

#define POLL_GROUP(C) \
  if (lane < 32) { \
    const int* fp = flags + ((C) * 32 + lane) * 16; \
    while (__hip_atomic_load(fp, __ATOMIC_RELAXED, __HIP_MEMORY_SCOPE_AGENT) < t) \
      __builtin_amdgcn_s_sleep(1); \
  }

#define MFMA_CHUNK(BUF, C) \
  { _Pragma("unroll") \
    for (int i = 0; i < 8; ++i) { \
      const int so = ((C) * 8 + i) * 1024 + kg * 256 + cc8; \
      const short8 bh = *reinterpret_cast<const short8*>(&UsH[so]); \
      const short8 bl = *reinterpret_cast<const short8*>(&UsL[so]); \
      acc = __builtin_amdgcn_mfma_f32_16x16x32_bf16(BUF[i], bh, acc, 0, 0, 0); \
      acc = __builtin_amdgcn_mfma_f32_16x16x32_bf16(BUF[i], bl, acc, 0, 0, 0); \
    } }

__global__ __launch_bounds__(512) void lstm_persist(const short* __restrict__ xzT,
                                                    const float* __restrict__ U,
                                                    short* __restrict__ h0buf,
                                                    short* __restrict__ h1buf,
                                                    int* __restrict__ flags,
                                                    float* __restrict__ out)
{
  extern __shared__ char smem[];
  short* UsH = (short*)smem;                       // [kb][c][k&7] 64 KiB
  short* UsL = (short*)(smem + 65536);             // 64 KiB
  float* zsm = (float*)(smem + 131072);            // [64][33]
  float* csm = (float*)(smem + 131072 + 8448);     // [64][8]

  const int tid  = threadIdx.x;
  const int lane = tid & 63, wave = tid >> 6;
  const int bid  = blockIdx.x;
  const int u0   = bid * 8;
  const int fr = lane & 15, kg = lane >> 4;
  const int mt = wave & 3;      // batch tile (16 rows)
  const int nt = wave >> 2;     // col tile (16 of 32 cols)
  const int cc8 = (nt * 16 + fr) * 8;
  const int gb = tid >> 3, guj = tid & 7;  // gate-math mapping

  // Stage U slice once (hi/lo bf16 split ~= fp32 accuracy).
  for (int idx = tid; idx < 1024 * 32; idx += 512) {
    const int k = idx >> 5, c = idx & 31;
    const int g = c >> 3, uj = c & 7;
    const float v = U[(size_t)k * NG + g * NH + u0 + uj];
    const short hi = f2bs(v);
    const short lo = f2bs(v - bs2f(hi));
    const int off = ((k >> 3) * 32 + c) * 8 + (k & 7);
    UsH[off] = hi; UsL[off] = lo;
  }
  csm[tid] = 0.f;
  __syncthreads();

  for (int t = 0; t < T_; ++t) {
    const short* __restrict__ hprev = (t & 1) ? h0buf : h1buf;
    short* __restrict__ hnext       = (t & 1) ? h1buf : h0buf;

    // Step's xz for this thread: 4 contiguous bf16 (one 8B load, oldest in vmcnt FIFO).
    const short4v xzv = *reinterpret_cast<const short4v*>(
        &xzT[(((size_t)bid * 256 + t) * 64 + gb) * 32 + guj * 4]);

    if (t > 0) {
      f32x4 acc = {0.f, 0.f, 0.f, 0.f};
      const short* hp = hprev + (size_t)(mt * 16 + fr) * NH + kg * 8;
      short8 ha[8], hb[8];
      POLL_GROUP(0); H_ISSUE(ha, 0, 64, 128, 192, 256, 320, 384, 448);
      POLL_GROUP(1); H_ISSUE(hb, 512, 576, 640, 704, 768, 832, 896, 960);
      WAITV(8);  MFMA_CHUNK(ha, 0);
      POLL_GROUP(2); H_ISSUE(ha, 1024, 1088, 1152, 1216, 1280, 1344, 1408, 1472);
      WAITV(8);  MFMA_CHUNK(hb, 1);
      POLL_GROUP(3); H_ISSUE(hb, 1536, 1600, 1664, 1728, 1792, 1856, 1920, 1984);
      WAITV(8);  MFMA_CHUNK(ha, 2);
      WAITV(0);  MFMA_CHUNK(hb, 3);
      // C/D: col = lane&15, row = (lane>>4)*4 + r
      #pragma unroll
      for (int r = 0; r < 4; ++r)
        zsm[(mt * 16 + kg * 4 + r) * 33 + nt * 16 + fr] = acc[r];
    }
    __syncthreads();

    {  // gate math: thread = (b=gb, uj=guj)
      const float zi = bs2f(xzv[0]) + ((t > 0) ? zsm[gb * 33 + guj]      : 0.f);
      const float zf = bs2f(xzv[1]) + ((t > 0) ? zsm[gb * 33 + 8 + guj]  : 0.f);
      const float zg = bs2f(xzv[2]) + ((t > 0) ? zsm[gb * 33 + 16 + guj] : 0.f);
      const float zo = bs2f(xzv[3]) + ((t > 0) ? zsm[gb * 33 + 24 + guj] : 0.f);
      const float ig = fsigm(zi);
      const float fg = fsigm(zf);
      const float gg = ftanh(zg);
      const float og = fsigm(zo);
      const float cc = fg * csm[tid] + ig * gg;
      const float hh = og * ftanh(cc);
      csm[tid] = cc;

      // h store: pack 2 bf16 -> u32, write-through sc0 sc1
      const short hb16 = f2bs(hh);
      const int partner = __shfl_xor((int)(uint16_t)hb16, 1);
      if (!(lane & 1)) {
        const uint32_t word = (uint32_t)(uint16_t)hb16 | ((uint32_t)partner << 16);
        uint32_t* hp32 = (uint32_t*)(hnext + (size_t)gb * NH + u0 + guj);
        asm volatile("global_store_dword %0, %1, off sc0 sc1" :: "v"(hp32), "v"(word) : "memory");
      }
      out[((size_t)gb * T_ + t) * NH + u0 + guj] = hh;
      asm volatile("s_waitcnt vmcnt(0)" ::: "memory");
      __builtin_amdgcn_sched_barrier(0);
    }
    __syncthreads();   // all waves' h stores drained & globally visible

    if (t < T_ - 1 && tid == 0)
      __hip_atomic_store(&flags[bid * 16], t + 1, __ATOMIC_RELAXED, __HIP_MEMORY_SCOPE_AGENT);
  }
}

extern "C" void kernel_launch(void* const* d_in, const int* in_sizes, int n_in,
                              void* d_out, int out_size, void* d_ws, size_t ws_size,
                              hipStream_t stream) {
  const float* x    = (const float*)d_in[0];
  const float* W    = (const float*)d_in[1];
  const float* U    = (const float*)d_in[2];
  const float* bias = (const float*)d_in[3];
  float* out = (float*)d_out;
  char* ws = (char*)d_ws;

  // ws: xzT bf16 128 MiB | flags 8 KiB | h ping/pong 2 x 128 KiB
  short* xzT   = (short*)ws;
  int*   flags = (int*)(ws + 134217728);
  short* hA    = (short*)(ws + 134225920);
  short* hB    = (short*)(ws + 134356992);

  hipMemsetAsync(flags, 0, NBLK * 16 * sizeof(int), stream);
  xz_gemm<<<dim3(128, 32), 256, 0, stream>>>(x, W, bias, xzT);

  hipFuncSetAttribute((const void*)lstm_persist,
                      hipFuncAttributeMaxDynamicSharedMemorySize, LDS_BYTES);
  lstm_persist<<<dim3(NBLK), dim3(512), LDS_BYTES, stream>>>(xzT, U, hA, hB, flags, out);
}